// Round 5
// baseline (261.785 us; speedup 1.0000x reference)
//
#include <hip/hip_runtime.h>
#include <stdint.h>
#include <limits.h>

constexpr int NB = 128; // batch

// ---------------- weight sign packing ----------------
__global__ void pack_weights_kernel(const float* __restrict__ w, uint32_t* __restrict__ out,
                                    int OC, int ICW)
{
    int idx = blockIdx.x * blockDim.x + threadIdx.x;
    int total = OC * 9 * ICW;
    if (idx >= total) return;
    int iw = idx % ICW;
    int t  = (idx / ICW) % 9;
    int oc = idx / (9 * ICW);
    int IC = ICW * 32;
    uint32_t word = 0;
    for (int b = 0; b < 32; ++b) {
        float wv = w[(size_t)(oc * IC + (iw * 32 + b)) * 9 + t];
        word |= (wv > 0.f ? 1u : 0u) << b;
    }
    out[idx] = word;
}

// ---------------- generic zero ----------------
__global__ void zero_kernel(uint32_t* __restrict__ p, int n)
{
    int i = blockIdx.x * blockDim.x + threadIdx.x;
    int stride = gridDim.x * blockDim.x;
    for (; i < n; i += stride) p[i] = 0u;
}

// ---------------- stage 1 helpers ----------------
__device__ __forceinline__ void conv1_load9(const float* __restrict__ x, int p, float* xv)
{
    int n = p >> 14;
    int y = (p >> 7) & 127;
    int c = p & 127;
    const float* xn = x + (size_t)n * 16384;
    #pragma unroll
    for (int ky = 0; ky < 3; ++ky)
    #pragma unroll
    for (int kx = 0; kx < 3; ++kx) {
        int yy = y + ky - 1, cc = c + kx - 1;
        float v = 0.f;
        if (yy >= 0 && yy < 128 && cc >= 0 && cc < 128) v = xn[yy * 128 + cc];
        xv[ky * 3 + kx] = v;
    }
}

// ---------------- stage 1 stats via 9+45 cross-correlation sums ----------------
__global__ __launch_bounds__(256) void xcorr_kernel(const float* __restrict__ x,
                                                    float* __restrict__ partials)
{
    __shared__ float wbuf[4][64];
    int tid = threadIdx.x;
    float s[9], c[45];
    #pragma unroll
    for (int t = 0; t < 9; ++t) s[t] = 0.f;
    #pragma unroll
    for (int q = 0; q < 45; ++q) c[q] = 0.f;

    int base = blockIdx.x * 256 + tid;
    #pragma unroll 4
    for (int k = 0; k < 16; ++k) {
        float xv[9];
        conv1_load9(x, base + k * 131072, xv);
        #pragma unroll
        for (int t = 0; t < 9; ++t) {
            s[t] += xv[t];
            #pragma unroll
            for (int u = t; u < 9; ++u) {
                int q = t * (19 - t) / 2 + (u - t);
                c[q] = fmaf(xv[t], xv[u], c[q]);
            }
        }
    }
    #pragma unroll
    for (int t = 0; t < 9; ++t) {
        float a = s[t];
        #pragma unroll
        for (int off = 32; off >= 1; off >>= 1) a += __shfl_xor(a, off, 64);
        s[t] = a;
    }
    #pragma unroll
    for (int q = 0; q < 45; ++q) {
        float a = c[q];
        #pragma unroll
        for (int off = 32; off >= 1; off >>= 1) a += __shfl_xor(a, off, 64);
        c[q] = a;
    }
    int lane = tid & 63, wv = tid >> 6;
    if (lane == 0) {
        #pragma unroll
        for (int t = 0; t < 9; ++t) wbuf[wv][t] = s[t];
        #pragma unroll
        for (int q = 0; q < 45; ++q) wbuf[wv][9 + q] = c[q];
    }
    __syncthreads();
    if (tid < 54)
        partials[blockIdx.x * 64 + tid] =
            (wbuf[0][tid] + wbuf[1][tid]) + (wbuf[2][tid] + wbuf[3][tid]);
}

__global__ void compute_ss1_kernel(const double* __restrict__ dsums,
                                   const float* __restrict__ w1, const float* __restrict__ b1,
                                   const float* __restrict__ g1, const float* __restrict__ be1,
                                   float* __restrict__ ss)
{
    __shared__ double S[9], C[45];
    int tid = threadIdx.x;
    if (tid < 9) S[tid] = dsums[tid];
    else if (tid < 54) C[tid - 9] = dsums[tid];
    __syncthreads();
    if (tid >= 32) return;
    double b = (double)b1[tid];
    double w[9];
    #pragma unroll
    for (int t = 0; t < 9; ++t) w[t] = (double)w1[tid * 9 + t];
    double Sdot = 0.0, Q = 0.0;
    #pragma unroll
    for (int t = 0; t < 9; ++t) {
        Sdot += w[t] * S[t];
        #pragma unroll
        for (int u = t; u < 9; ++u) {
            int q = t * (19 - t) / 2 + (u - t);
            double term = w[t] * w[u] * C[q];
            Q += (u == t) ? term : 2.0 * term;
        }
    }
    const double N = 2097152.0;
    double mu  = Sdot / N + b;
    double ex2 = (Q + 2.0 * b * Sdot) / N + b * b;
    float var = (float)(ex2 - mu * mu);
    float A = g1[tid] * (1.f / sqrtf(var + 1e-5f));
    ss[tid] = A;
    ss[32 + tid] = be1[tid] - (float)mu * A;
}

// float partials -> double sums (xcorr path)
template<int CH, int STRIDE>
__global__ __launch_bounds__(256) void reduce_partials_kernel(
    const float* __restrict__ partials, int nblk, double* __restrict__ dsums)
{
    __shared__ double wsum[4];
    int ch = blockIdx.x;
    int tid = threadIdx.x;
    double a = 0.0;
    for (int i = tid; i < nblk; i += 256)
        a += (double)partials[(size_t)i * STRIDE + ch];
    #pragma unroll
    for (int off = 32; off >= 1; off >>= 1)
        a += __shfl_xor(a, off, 64);
    if ((tid & 63) == 0) wsum[tid >> 6] = a;
    __syncthreads();
    if (tid == 0)
        dsums[ch] = (wsum[0] + wsum[1]) + (wsum[2] + wsum[3]);
}

// ---------------- stage 1: conv 1->32, BN threshold, sign, pack -> PADDED s1 ----------------
__global__ __launch_bounds__(256) void conv1_pack2_kernel(
    const float* __restrict__ x, const float* __restrict__ w1, const float* __restrict__ b1,
    const float* __restrict__ ss, uint32_t* __restrict__ s1p)
{
    __shared__ float wl[32 * 12];
    __shared__ float abl[64];
    int tid = threadIdx.x;
    for (int i = tid; i < 288; i += 256) wl[(i / 9) * 12 + (i % 9)] = w1[i];
    if (tid < 32) {
        float A = ss[tid];
        abl[2 * tid] = A;
        abl[2 * tid + 1] = fmaf(A, b1[tid], ss[32 + tid]);
    }
    __syncthreads();
    int p = blockIdx.x * 256 + tid;
    float xv[9];
    conv1_load9(x, p, xv);
    int n = p >> 14, y = (p >> 7) & 127, c = p & 127;

    uint32_t word = 0;
    for (int oc = 0; oc < 32; ++oc) {
        float4 wa = *(const float4*)&wl[oc * 12];
        float4 wb = *(const float4*)&wl[oc * 12 + 4];
        float w8 = wl[oc * 12 + 8];
        float2 ab = *(const float2*)&abl[oc * 2];
        float a = xv[0] * wa.x;
        a = fmaf(xv[1], wa.y, a);
        a = fmaf(xv[2], wa.z, a);
        a = fmaf(xv[3], wa.w, a);
        a = fmaf(xv[4], wb.x, a);
        a = fmaf(xv[5], wb.y, a);
        a = fmaf(xv[6], wb.z, a);
        a = fmaf(xv[7], wb.w, a);
        a = fmaf(xv[8], w8, a);
        float v = fmaf(ab.x, a, ab.y);
        word |= (v > 0.f ? 1u : 0u) << oc;
    }
    s1p[(size_t)n * 16900 + (y + 1) * 130 + (c + 1)] = word;
}

// ---------------- main binconv+pool (interior-exact, unmasked) -> int16 pairs ----------------
template<int OC, int PW, int LPW>
__global__ __launch_bounds__(256) void binconv_main_kernel(
    const uint32_t* __restrict__ sp_in, const uint32_t* __restrict__ wp,
    const float* __restrict__ alpha, uint32_t* __restrict__ m16)
{
    constexpr int PS = 2 * PW + 2;
    constexpr int TOTAL = NB * PW * PW;
    __shared__ uint32_t wl[OC * 12];
    int tid = threadIdx.x;
    for (int i = tid; i < OC * 9; i += 256) wl[(i / 9) * 12 + (i % 9)] = wp[i];
    __syncthreads();
    bool useMax = (alpha[0] >= 0.f);
    int p = blockIdx.x * 256 + tid;
    int px = p & (PW - 1), py = (p >> LPW) & (PW - 1), n = p >> (2 * LPW);
    const uint32_t* base = sp_in + (size_t)n * PS * PS + (2 * py) * PS + 2 * px;

    uint32_t xw[16];
    #pragma unroll
    for (int r = 0; r < 4; ++r) {
        uint2 a = *(const uint2*)(base + r * PS);
        uint2 b = *(const uint2*)(base + r * PS + 2);
        xw[r * 4 + 0] = a.x; xw[r * 4 + 1] = a.y;
        xw[r * 4 + 2] = b.x; xw[r * 4 + 3] = b.y;
    }

    uint32_t pend = 0;
    for (int oc = 0; oc < OC; ++oc) {
        uint4 wa = *(const uint4*)&wl[oc * 12];
        uint4 wb = *(const uint4*)&wl[oc * 12 + 4];
        uint32_t w8 = wl[oc * 12 + 8];
        uint32_t w[9] = {wa.x, wa.y, wa.z, wa.w, wb.x, wb.y, wb.z, wb.w, w8};
        int s0 = 0, s1 = 0, s2 = 0, s3 = 0;
        #pragma unroll
        for (int ky = 0; ky < 3; ++ky)
        #pragma unroll
        for (int kx = 0; kx < 3; ++kx) {
            uint32_t wt = w[ky * 3 + kx];
            s0 += __popc(xw[ky * 4 + kx]           ^ wt);
            s1 += __popc(xw[ky * 4 + kx + 1]       ^ wt);
            s2 += __popc(xw[(ky + 1) * 4 + kx]     ^ wt);
            s3 += __popc(xw[(ky + 1) * 4 + kx + 1] ^ wt);
        }
        int sm = useMax ? min(min(s0, s1), min(s2, s3))
                        : max(max(s0, s1), max(s2, s3));
        int m = 288 - 2 * sm;
        if ((oc & 1) == 0) pend = (uint32_t)(uint16_t)(short)m;
        else m16[(size_t)(oc >> 1) * TOTAL + p] = pend | ((uint32_t)(uint16_t)(short)m << 16);
    }
}

// ---------------- border fix: recompute ring pixels with masks ----------------
template<int OC, int PW>
__global__ __launch_bounds__(256) void binconv_fix_kernel(
    const uint32_t* __restrict__ sp_in, const uint32_t* __restrict__ wp,
    const float* __restrict__ alpha, uint32_t* __restrict__ m16)
{
    constexpr int PS = 2 * PW + 2;
    constexpr int TOTAL = NB * PW * PW;
    constexpr int RING = 4 * PW - 4;
    __shared__ uint32_t wl[OC * 12];
    int tid = threadIdx.x;
    for (int i = tid; i < OC * 9; i += 256) wl[(i / 9) * 12 + (i % 9)] = wp[i];
    __syncthreads();
    bool useMax = (alpha[0] >= 0.f);
    int t = blockIdx.x * 256 + tid;
    int n = t / RING, r = t % RING;
    int py, px;
    if (r < PW)              { py = 0;      px = r; }
    else if (r < 2 * PW)     { py = PW - 1; px = r - PW; }
    else if (r < 3 * PW - 2) { px = 0;      py = r - 2 * PW + 1; }
    else                     { px = PW - 1; py = r - (3 * PW - 2) + 1; }
    int p = n * PW * PW + py * PW + px;
    const uint32_t* base = sp_in + (size_t)n * PS * PS + (2 * py) * PS + 2 * px;

    uint32_t xw[16], wm[16];
    #pragma unroll
    for (int a = 0; a < 4; ++a) {
        int rr = 2 * py - 1 + a;
        bool rv = (rr >= 0) && (rr < 2 * PW);
        #pragma unroll
        for (int b = 0; b < 4; ++b) {
            int cc = 2 * px - 1 + b;
            bool v = rv && (cc >= 0) && (cc < 2 * PW);
            wm[a * 4 + b] = v ? 0xFFFFFFFFu : 0u;
            xw[a * 4 + b] = base[a * PS + b];
        }
    }
    int cnt[4];
    #pragma unroll
    for (int a2 = 0; a2 < 2; ++a2)
    #pragma unroll
    for (int b2 = 0; b2 < 2; ++b2) {
        int cc = 0;
        #pragma unroll
        for (int ky = 0; ky < 3; ++ky)
        #pragma unroll
        for (int kx = 0; kx < 3; ++kx)
            cc += (int)(wm[(a2 + ky) * 4 + (b2 + kx)] & 1u);
        cnt[a2 * 2 + b2] = cc * 32;
    }

    uint32_t pend = 0;
    for (int oc = 0; oc < OC; ++oc) {
        uint4 wa = *(const uint4*)&wl[oc * 12];
        uint4 wb = *(const uint4*)&wl[oc * 12 + 4];
        uint32_t w8 = wl[oc * 12 + 8];
        uint32_t w[9] = {wa.x, wa.y, wa.z, wa.w, wb.x, wb.y, wb.z, wb.w, w8};
        int v[4];
        #pragma unroll
        for (int a2 = 0; a2 < 2; ++a2)
        #pragma unroll
        for (int b2 = 0; b2 < 2; ++b2) {
            int pop = 0;
            #pragma unroll
            for (int ky = 0; ky < 3; ++ky)
            #pragma unroll
            for (int kx = 0; kx < 3; ++kx) {
                int idx = (a2 + ky) * 4 + (b2 + kx);
                pop += __popc((xw[idx] ^ w[ky * 3 + kx]) & wm[idx]);
            }
            v[a2 * 2 + b2] = cnt[a2 * 2 + b2] - 2 * pop;
        }
        int m = useMax ? max(max(v[0], v[1]), max(v[2], v[3]))
                       : min(min(v[0], v[1]), min(v[2], v[3]));
        if ((oc & 1) == 0) pend = (uint32_t)(uint16_t)(short)m;
        else m16[(size_t)(oc >> 1) * TOTAL + p] = pend | ((uint32_t)(uint16_t)(short)m << 16);
    }
}

// ---------------- integer BN stats over m16 planes ----------------
template<int PIXELS, int CHUNKS>
__global__ __launch_bounds__(256) void stats16_kernel(const uint32_t* __restrict__ m16,
                                                      double* __restrict__ pd)
{
    __shared__ int wb[4][4];
    int bid = blockIdx.x;
    int q = bid / CHUNKS, ch = bid % CHUNKS;
    const uint32_t* pl = m16 + (size_t)q * PIXELS + (size_t)ch * (PIXELS / CHUNKS);
    int tid = threadIdx.x;
    int s0 = 0, s1 = 0, q0 = 0, q1 = 0;
    #pragma unroll 4
    for (int j = 0; j < PIXELS / CHUNKS / 256; ++j) {
        uint32_t u = pl[tid + j * 256];
        int m0 = (int)(short)(u & 0xffffu);
        int m1 = (int)u >> 16;
        s0 += m0; s1 += m1;
        q0 += m0 * m0; q1 += m1 * m1;
    }
    #pragma unroll
    for (int off = 32; off >= 1; off >>= 1) {
        s0 += __shfl_xor(s0, off, 64); s1 += __shfl_xor(s1, off, 64);
        q0 += __shfl_xor(q0, off, 64); q1 += __shfl_xor(q1, off, 64);
    }
    int lane = tid & 63, w = tid >> 6;
    if (lane == 0) { wb[w][0] = s0; wb[w][1] = s1; wb[w][2] = q0; wb[w][3] = q1; }
    __syncthreads();
    if (tid < 4)
        pd[(size_t)bid * 4 + tid] =
            (double)((long long)wb[0][tid] + wb[1][tid] + wb[2][tid] + wb[3][tid]);
}

template<int OC, int CHUNKS>
__global__ void reduce_stats16_kernel(const double* __restrict__ pd, double* __restrict__ dsums)
{
    int ch = blockIdx.x;
    bool issq = ch >= OC;
    int c = issq ? ch - OC : ch;
    int q = c >> 1;
    int slot = (issq ? 2 : 0) + (c & 1);
    int tid = threadIdx.x;
    double a = (tid < CHUNKS) ? pd[(size_t)(q * CHUNKS + tid) * 4 + slot] : 0.0;
    #pragma unroll
    for (int off = 32; off >= 1; off >>= 1)
        a += __shfl_xor(a, off, 64);
    if (tid == 0) dsums[ch] = a;
}

template<int OC>
__global__ void compute_ss_alpha_kernel(const double* __restrict__ dsums,
                                        const float* __restrict__ gamma, const float* __restrict__ beta,
                                        const float* __restrict__ alpha,
                                        float inv_n, float* __restrict__ ss)
{
    int tid = threadIdx.x;
    if (tid >= OC) return;
    double al = (double)alpha[0];
    float mu  = (float)(dsums[tid] * al * (double)inv_n);
    float ex2 = (float)(dsums[OC + tid] * al * al * (double)inv_n);
    float var = ex2 - mu * mu;
    float A = gamma[tid] * (1.f / sqrtf(var + 1e-5f));
    ss[tid] = A;
    ss[OC + tid] = beta[tid] - mu * A;
}

// ---------------- thin pack: int16 -> BN threshold -> sign bits ----------------
template<int OC, int PW, int LPW, bool PADOUT>
__global__ __launch_bounds__(256) void binconv_pack_kernel(
    const uint32_t* __restrict__ m16, const float* __restrict__ alpha,
    const float* __restrict__ ss, void* __restrict__ sout)
{
    constexpr int TOTAL = NB * PW * PW;
    __shared__ float Ap[OC], Bp[OC];
    int tid = threadIdx.x;
    if (tid < OC) { Ap[tid] = ss[tid] * alpha[0]; Bp[tid] = ss[OC + tid]; }
    __syncthreads();
    int p = blockIdx.x * 256 + tid;
    uint64_t word = 0;
    #pragma unroll
    for (int q = 0; q < OC / 2; ++q) {
        uint32_t u = m16[(size_t)q * TOTAL + p];
        int m0 = (int)(short)(u & 0xffffu);
        int m1 = (int)u >> 16;
        float v0 = fmaf(Ap[2 * q],     (float)m0, Bp[2 * q]);
        float v1 = fmaf(Ap[2 * q + 1], (float)m1, Bp[2 * q + 1]);
        word |= (v0 > 0.f ? 1ull : 0ull) << (2 * q);
        word |= (v1 > 0.f ? 1ull : 0ull) << (2 * q + 1);
    }
    if constexpr (PADOUT) {
        int px = p & (PW - 1), py = (p >> LPW) & (PW - 1), n = p >> (2 * LPW);
        ((uint32_t*)sout)[(size_t)n * (PW + 2) * (PW + 2) + (py + 1) * (PW + 2) + (px + 1)]
            = (uint32_t)word;
    } else {
        ((uint64_t*)sout)[p] = word;
    }
}

// ---------------- stage 4: binary conv 64->128, slab partials ----------------
__global__ __launch_bounds__(256) void conv4_partial_kernel(
    const uint64_t* __restrict__ s3, const uint64_t* __restrict__ wp4,
    float* __restrict__ p4)
{
    __shared__ uint64_t xt[192];
    __shared__ uint64_t wl[1152];
    __shared__ float red[256];
    int b = blockIdx.x;
    int n = b >> 3, s = b & 7;
    int tid = threadIdx.x;
    for (int i = tid; i < 192; i += 256) {
        int row = 4 * s - 1 + (i >> 5);
        int col = i & 31;
        xt[i] = (row >= 0 && row < 32) ? s3[(size_t)n * 1024 + row * 32 + col] : 0ull;
    }
    for (int i = tid; i < 1152; i += 256) wl[i] = wp4[i];
    __syncthreads();
    int oc = tid & 127, h = tid >> 7;
    uint64_t wr[9];
    #pragma unroll
    for (int t = 0; t < 9; ++t) wr[t] = wl[oc * 9 + t];
    int acc = 0;
    #pragma unroll
    for (int ry = 0; ry < 2; ++ry) {
        int lry = 2 * h + ry;
        int y = 4 * s + lry;
        for (int x = 0; x < 32; ++x) {
            int pop = 0, c = 0;
            #pragma unroll
            for (int ky = 0; ky < 3; ++ky) {
                int yy = y + ky - 1;
                if (yy < 0 || yy >= 32) continue;
                int lrow = lry + ky;
                #pragma unroll
                for (int kx = 0; kx < 3; ++kx) {
                    int xx = x + kx - 1;
                    if (xx < 0 || xx >= 32) continue;
                    pop += __popcll(xt[lrow * 32 + xx] ^ wr[ky * 3 + kx]);
                    c += 64;
                }
            }
            acc += c - 2 * pop;
        }
    }
    red[tid] = (float)acc;
    __syncthreads();
    if (tid < 128)
        p4[(size_t)b * 128 + tid] = red[tid] + red[tid + 128];
}

__global__ void mean4_kernel(const float* __restrict__ p4, const float* __restrict__ alpha4,
                             float* __restrict__ mean4)
{
    int t = blockIdx.x * blockDim.x + threadIdx.x;
    if (t >= NB * 128) return;
    int n = t >> 7, oc = t & 127;
    float a = 0.f;
    #pragma unroll
    for (int s = 0; s < 8; ++s)
        a += p4[(size_t)((n * 8 + s) * 128) + oc];
    mean4[t] = a * alpha4[0] * (1.f / 1024.f);
}

__global__ void linear_kernel(const float* __restrict__ mean4, const float* __restrict__ wf,
                              const float* __restrict__ bf, float* __restrict__ out)
{
    int t = blockIdx.x * blockDim.x + threadIdx.x;
    if (t >= 1280) return;
    int n = t / 10, k = t % 10;
    const float* m = mean4 + n * 128;
    const float* w = wf + k * 128;
    float a = bf[k];
    #pragma unroll 4
    for (int i = 0; i < 128; ++i) a = fmaf(m[i], w[i], a);
    out[t] = a;
}

extern "C" void kernel_launch(void* const* d_in, const int* in_sizes, int n_in,
                              void* d_out, int out_size, void* d_ws, size_t ws_size,
                              hipStream_t stream)
{
    const float* x   = (const float*)d_in[0];
    const float* w1  = (const float*)d_in[1];
    const float* b1  = (const float*)d_in[2];
    const float* g1  = (const float*)d_in[3];
    const float* be1 = (const float*)d_in[4];
    const float* w2  = (const float*)d_in[5];
    const float* a2  = (const float*)d_in[6];
    const float* g2  = (const float*)d_in[7];
    const float* be2 = (const float*)d_in[8];
    const float* w3  = (const float*)d_in[9];
    const float* a3  = (const float*)d_in[10];
    const float* g3  = (const float*)d_in[11];
    const float* be3 = (const float*)d_in[12];
    const float* w4  = (const float*)d_in[13];
    const float* a4  = (const float*)d_in[14];
    const float* wf  = (const float*)d_in[15];
    const float* bf  = (const float*)d_in[16];
    float* out = (float*)d_out;

    uint8_t* ws = (uint8_t*)d_ws;
    size_t off = 0;
    auto alloc = [&](size_t bytes) -> void* {
        void* p = ws + off;
        off += (bytes + 255) & ~(size_t)255;
        return p;
    };
    uint32_t* wp2 = (uint32_t*)alloc(288 * 4);
    uint32_t* wp3 = (uint32_t*)alloc(576 * 4);
    uint32_t* wp4 = (uint32_t*)alloc(2304 * 4);
    float* ss1 = (float*)alloc(64 * 4);
    float* ss2 = (float*)alloc(64 * 4);
    float* ss3 = (float*)alloc(128 * 4);
    double* dsums = (double*)alloc(256 * 8);
    double* pd    = (double*)alloc(2048 * 8);
    float* partials = (float*)alloc((size_t)512 * 64 * 4);
    uint32_t* s1p = (uint32_t*)alloc((size_t)128 * 16900 * 4);   // padded 130x130
    uint32_t* s2p = (uint32_t*)alloc((size_t)128 * 4356 * 4);    // padded 66x66
    uint64_t* s3  = (uint64_t*)alloc((size_t)128 * 1024 * 8);    // unpadded 32x32
    float* mean4 = (float*)alloc((size_t)128 * 128 * 4);
    float* p4    = (float*)alloc((size_t)1024 * 128 * 4);
    uint32_t* m16_2 = (uint32_t*)alloc((size_t)16 * 524288 * 4); // 33.6 MB
    uint32_t* m16_3 = (uint32_t*)alloc((size_t)32 * 131072 * 4); // 16.8 MB

    // zero padded buffers (borders must be 0 = "pad" encoding)
    zero_kernel<<<2048, 256, 0, stream>>>(s1p, 128 * 16900);
    zero_kernel<<<1024, 256, 0, stream>>>(s2p, 128 * 4356);

    // pack weight signs
    pack_weights_kernel<<<2, 256, 0, stream>>>(w2, wp2, 32, 1);
    pack_weights_kernel<<<3, 256, 0, stream>>>(w3, wp3, 64, 1);
    pack_weights_kernel<<<9, 256, 0, stream>>>(w4, wp4, 128, 2);

    // stage 1: xcorr stats -> BN scale/shift -> conv+sign+pack (padded out)
    xcorr_kernel<<<512, 256, 0, stream>>>(x, partials);
    reduce_partials_kernel<54, 64><<<54, 256, 0, stream>>>(partials, 512, dsums);
    compute_ss1_kernel<<<1, 64, 0, stream>>>(dsums, w1, b1, g1, be1, ss1);
    conv1_pack2_kernel<<<8192, 256, 0, stream>>>(x, w1, b1, ss1, s1p);

    // stage 2: unmasked main + border fix -> int stats -> BN -> pack (padded out)
    binconv_main_kernel<32, 64, 6><<<2048, 256, 0, stream>>>(s1p, wp2, a2, m16_2);
    binconv_fix_kernel<32, 64><<<126, 256, 0, stream>>>(s1p, wp2, a2, m16_2);
    stats16_kernel<524288, 32><<<512, 256, 0, stream>>>(m16_2, pd);
    reduce_stats16_kernel<32, 32><<<64, 64, 0, stream>>>(pd, dsums);
    compute_ss_alpha_kernel<32><<<1, 32, 0, stream>>>(dsums, g2, be2, a2, 1.f / 524288.f, ss2);
    binconv_pack_kernel<32, 64, 6, true><<<2048, 256, 0, stream>>>(m16_2, a2, ss2, (void*)s2p);

    // stage 3
    binconv_main_kernel<64, 32, 5><<<512, 256, 0, stream>>>(s2p, wp3, a3, m16_3);
    binconv_fix_kernel<64, 32><<<62, 256, 0, stream>>>(s2p, wp3, a3, m16_3);
    stats16_kernel<131072, 8><<<256, 256, 0, stream>>>(m16_3, pd);
    reduce_stats16_kernel<64, 8><<<128, 64, 0, stream>>>(pd, dsums);
    compute_ss_alpha_kernel<64><<<1, 64, 0, stream>>>(dsums, g3, be3, a3, 1.f / 131072.f, ss3);
    binconv_pack_kernel<64, 32, 5, false><<<512, 256, 0, stream>>>(m16_3, a3, ss3, (void*)s3);

    // stage 4: slab partials -> mean -> classifier
    conv4_partial_kernel<<<1024, 256, 0, stream>>>(s3, (const uint64_t*)wp4, p4);
    mean4_kernel<<<64, 256, 0, stream>>>(p4, a4, mean4);
    linear_kernel<<<5, 256, 0, stream>>>(mean4, wf, bf, out);
}

// Round 6
// 221.913 us; speedup vs baseline: 1.1797x; 1.1797x over previous
//
#include <hip/hip_runtime.h>
#include <stdint.h>

constexpr int NB = 128; // batch

// ---------------- weight sign packing (all three layers, one kernel) ----------------
__global__ void pack_weights_all_kernel(const float* __restrict__ w2, const float* __restrict__ w3,
                                        const float* __restrict__ w4,
                                        uint32_t* __restrict__ wp2, uint32_t* __restrict__ wp3,
                                        uint32_t* __restrict__ wp4)
{
    int idx = blockIdx.x * blockDim.x + threadIdx.x;
    const float* w; uint32_t* o; int ICW, i;
    if (idx < 288)       { w = w2; o = wp2; ICW = 1; i = idx; }
    else if (idx < 864)  { w = w3; o = wp3; ICW = 1; i = idx - 288; }
    else if (idx < 3168) { w = w4; o = wp4; ICW = 2; i = idx - 864; }
    else return;
    int iw = i % ICW;
    int t  = (i / ICW) % 9;
    int oc = i / (9 * ICW);
    int IC = ICW * 32;
    uint32_t word = 0;
    for (int b = 0; b < 32; ++b) {
        float wv = w[(size_t)(oc * IC + (iw * 32 + b)) * 9 + t];
        word |= (wv > 0.f ? 1u : 0u) << b;
    }
    o[i] = word;
}

// ---------------- zero (uint4 grid-stride) ----------------
__global__ void zero4_kernel(uint4* __restrict__ p, int n4)
{
    int i = blockIdx.x * blockDim.x + threadIdx.x;
    int stride = gridDim.x * blockDim.x;
    uint4 z = {0u, 0u, 0u, 0u};
    for (; i < n4; i += stride) p[i] = z;
}

// ---------------- stage 1 helpers ----------------
__device__ __forceinline__ void conv1_load9(const float* __restrict__ x, int p, float* xv)
{
    int n = p >> 14;
    int y = (p >> 7) & 127;
    int c = p & 127;
    const float* xn = x + (size_t)n * 16384;
    #pragma unroll
    for (int ky = 0; ky < 3; ++ky)
    #pragma unroll
    for (int kx = 0; kx < 3; ++kx) {
        int yy = y + ky - 1, cc = c + kx - 1;
        float v = 0.f;
        if (yy >= 0 && yy < 128 && cc >= 0 && cc < 128) v = xn[yy * 128 + cc];
        xv[ky * 3 + kx] = v;
    }
}

// ---------------- stage 1 stats via 9+45 cross-correlation sums ----------------
__global__ __launch_bounds__(256) void xcorr_kernel(const float* __restrict__ x,
                                                    float* __restrict__ partials)
{
    __shared__ float wbuf[4][64];
    int tid = threadIdx.x;
    float s[9], c[45];
    #pragma unroll
    for (int t = 0; t < 9; ++t) s[t] = 0.f;
    #pragma unroll
    for (int q = 0; q < 45; ++q) c[q] = 0.f;

    int base = blockIdx.x * 256 + tid;
    #pragma unroll 4
    for (int k = 0; k < 16; ++k) {
        float xv[9];
        conv1_load9(x, base + k * 131072, xv);
        #pragma unroll
        for (int t = 0; t < 9; ++t) {
            s[t] += xv[t];
            #pragma unroll
            for (int u = t; u < 9; ++u) {
                int q = t * (19 - t) / 2 + (u - t);
                c[q] = fmaf(xv[t], xv[u], c[q]);
            }
        }
    }
    #pragma unroll
    for (int t = 0; t < 9; ++t) {
        float a = s[t];
        #pragma unroll
        for (int off = 32; off >= 1; off >>= 1) a += __shfl_xor(a, off, 64);
        s[t] = a;
    }
    #pragma unroll
    for (int q = 0; q < 45; ++q) {
        float a = c[q];
        #pragma unroll
        for (int off = 32; off >= 1; off >>= 1) a += __shfl_xor(a, off, 64);
        c[q] = a;
    }
    int lane = tid & 63, wv = tid >> 6;
    if (lane == 0) {
        #pragma unroll
        for (int t = 0; t < 9; ++t) wbuf[wv][t] = s[t];
        #pragma unroll
        for (int q = 0; q < 45; ++q) wbuf[wv][9 + q] = c[q];
    }
    __syncthreads();
    if (tid < 54)
        partials[blockIdx.x * 64 + tid] =
            (wbuf[0][tid] + wbuf[1][tid]) + (wbuf[2][tid] + wbuf[3][tid]);
}

__global__ void compute_ss1_kernel(const double* __restrict__ dsums,
                                   const float* __restrict__ w1, const float* __restrict__ b1,
                                   const float* __restrict__ g1, const float* __restrict__ be1,
                                   float* __restrict__ ss)
{
    __shared__ double S[9], C[45];
    int tid = threadIdx.x;
    if (tid < 9) S[tid] = dsums[tid];
    else if (tid < 54) C[tid - 9] = dsums[tid];
    __syncthreads();
    if (tid >= 32) return;
    double b = (double)b1[tid];
    double w[9];
    #pragma unroll
    for (int t = 0; t < 9; ++t) w[t] = (double)w1[tid * 9 + t];
    double Sdot = 0.0, Q = 0.0;
    #pragma unroll
    for (int t = 0; t < 9; ++t) {
        Sdot += w[t] * S[t];
        #pragma unroll
        for (int u = t; u < 9; ++u) {
            int q = t * (19 - t) / 2 + (u - t);
            double term = w[t] * w[u] * C[q];
            Q += (u == t) ? term : 2.0 * term;
        }
    }
    const double N = 2097152.0;
    double mu  = Sdot / N + b;
    double ex2 = (Q + 2.0 * b * Sdot) / N + b * b;
    float var = (float)(ex2 - mu * mu);
    float A = g1[tid] * (1.f / sqrtf(var + 1e-5f));
    ss[tid] = A;
    ss[32 + tid] = be1[tid] - (float)mu * A;
}

// float partials -> double sums (xcorr path)
template<int CH, int STRIDE>
__global__ __launch_bounds__(256) void reduce_partials_kernel(
    const float* __restrict__ partials, int nblk, double* __restrict__ dsums)
{
    __shared__ double wsum[4];
    int ch = blockIdx.x;
    int tid = threadIdx.x;
    double a = 0.0;
    for (int i = tid; i < nblk; i += 256)
        a += (double)partials[(size_t)i * STRIDE + ch];
    #pragma unroll
    for (int off = 32; off >= 1; off >>= 1)
        a += __shfl_xor(a, off, 64);
    if ((tid & 63) == 0) wsum[tid >> 6] = a;
    __syncthreads();
    if (tid == 0)
        dsums[ch] = (wsum[0] + wsum[1]) + (wsum[2] + wsum[3]);
}

// ---------------- stage 1: conv 1->32, BN threshold, sign, pack -> PADDED s1 ----------------
// scalar (SGPR) weights: all per-oc data read via wave-uniform indices
__global__ __launch_bounds__(256) void conv1_pack2_kernel(
    const float* __restrict__ x, const float* __restrict__ w1, const float* __restrict__ b1,
    const float* __restrict__ ss, uint32_t* __restrict__ s1p)
{
    int p = blockIdx.x * 256 + threadIdx.x;
    float xv[9];
    conv1_load9(x, p, xv);
    int n = p >> 14, y = (p >> 7) & 127, c = p & 127;

    uint32_t word = 0;
    for (int oc = 0; oc < 32; ++oc) {
        float a = xv[0] * w1[oc * 9];
        #pragma unroll
        for (int t = 1; t < 9; ++t) a = fmaf(xv[t], w1[oc * 9 + t], a);
        float A = ss[oc];
        float Bc = fmaf(A, b1[oc], ss[32 + oc]);
        float v = fmaf(A, a, Bc);
        word |= (v > 0.f ? 1u : 0u) << oc;
    }
    s1p[(size_t)n * 16900 + (y + 1) * 130 + (c + 1)] = word;
}

// ---------------- fused main+fix binconv+pool -> int16 pairs ----------------
// blocks [0, MAINB): interior-exact unmasked path, border stores suppressed
// blocks [MAINB, MAINB+FIXB): masked recompute of the border ring
template<int OC, int PW, int LPW, int MAINB>
__global__ __launch_bounds__(256) void binconv_mainfix_kernel(
    const uint32_t* __restrict__ sp_in, const uint32_t* __restrict__ wp,
    const float* __restrict__ alpha, uint32_t* __restrict__ m16)
{
    constexpr int PS = 2 * PW + 2;
    constexpr int TOTAL = NB * PW * PW;
    int tid = threadIdx.x;
    bool useMax = (alpha[0] >= 0.f);

    if ((int)blockIdx.x < MAINB) {
        int p = blockIdx.x * 256 + tid;
        int px = p & (PW - 1), py = (p >> LPW) & (PW - 1), n = p >> (2 * LPW);
        bool border = (px == 0) | (px == PW - 1) | (py == 0) | (py == PW - 1);
        const uint32_t* base = sp_in + (size_t)n * PS * PS + (2 * py) * PS + 2 * px;

        uint32_t xw[16];
        #pragma unroll
        for (int r = 0; r < 4; ++r) {
            uint2 a = *(const uint2*)(base + r * PS);
            uint2 b = *(const uint2*)(base + r * PS + 2);
            xw[r * 4 + 0] = a.x; xw[r * 4 + 1] = a.y;
            xw[r * 4 + 2] = b.x; xw[r * 4 + 3] = b.y;
        }

        uint32_t pend = 0;
        for (int oc = 0; oc < OC; ++oc) {
            int s0 = 0, s1 = 0, s2 = 0, s3 = 0;
            #pragma unroll
            for (int ky = 0; ky < 3; ++ky)
            #pragma unroll
            for (int kx = 0; kx < 3; ++kx) {
                uint32_t wt = wp[oc * 9 + ky * 3 + kx];   // wave-uniform -> SGPR
                s0 += __popc(xw[ky * 4 + kx]           ^ wt);
                s1 += __popc(xw[ky * 4 + kx + 1]       ^ wt);
                s2 += __popc(xw[(ky + 1) * 4 + kx]     ^ wt);
                s3 += __popc(xw[(ky + 1) * 4 + kx + 1] ^ wt);
            }
            int sm = useMax ? min(min(s0, s1), min(s2, s3))
                            : max(max(s0, s1), max(s2, s3));
            int m = 288 - 2 * sm;
            if ((oc & 1) == 0) pend = (uint32_t)(uint16_t)(short)m;
            else if (!border)
                m16[(size_t)(oc >> 1) * TOTAL + p] = pend | ((uint32_t)(uint16_t)(short)m << 16);
        }
    } else {
        constexpr int RING = 4 * PW - 4;
        int t = ((int)blockIdx.x - MAINB) * 256 + tid;
        if (t >= NB * RING) return;
        int n = t / RING, r = t % RING;
        int py, px;
        if (r < PW)              { py = 0;      px = r; }
        else if (r < 2 * PW)     { py = PW - 1; px = r - PW; }
        else if (r < 3 * PW - 2) { px = 0;      py = r - 2 * PW + 1; }
        else                     { px = PW - 1; py = r - (3 * PW - 2) + 1; }
        int p = n * PW * PW + py * PW + px;
        const uint32_t* base = sp_in + (size_t)n * PS * PS + (2 * py) * PS + 2 * px;

        uint32_t xw[16], wm[16];
        #pragma unroll
        for (int a = 0; a < 4; ++a) {
            int rr = 2 * py - 1 + a;
            bool rv = (rr >= 0) && (rr < 2 * PW);
            #pragma unroll
            for (int b = 0; b < 4; ++b) {
                int cc = 2 * px - 1 + b;
                bool v = rv && (cc >= 0) && (cc < 2 * PW);
                wm[a * 4 + b] = v ? 0xFFFFFFFFu : 0u;
                xw[a * 4 + b] = base[a * PS + b];
            }
        }
        int cnt[4];
        #pragma unroll
        for (int a2 = 0; a2 < 2; ++a2)
        #pragma unroll
        for (int b2 = 0; b2 < 2; ++b2) {
            int cc = 0;
            #pragma unroll
            for (int ky = 0; ky < 3; ++ky)
            #pragma unroll
            for (int kx = 0; kx < 3; ++kx)
                cc += (int)(wm[(a2 + ky) * 4 + (b2 + kx)] & 1u);
            cnt[a2 * 2 + b2] = cc * 32;
        }

        uint32_t pend = 0;
        for (int oc = 0; oc < OC; ++oc) {
            int v[4];
            #pragma unroll
            for (int a2 = 0; a2 < 2; ++a2)
            #pragma unroll
            for (int b2 = 0; b2 < 2; ++b2) {
                int pop = 0;
                #pragma unroll
                for (int ky = 0; ky < 3; ++ky)
                #pragma unroll
                for (int kx = 0; kx < 3; ++kx) {
                    int idx = (a2 + ky) * 4 + (b2 + kx);
                    pop += __popc((xw[idx] ^ wp[oc * 9 + ky * 3 + kx]) & wm[idx]);
                }
                v[a2 * 2 + b2] = cnt[a2 * 2 + b2] - 2 * pop;
            }
            int m = useMax ? max(max(v[0], v[1]), max(v[2], v[3]))
                           : min(min(v[0], v[1]), min(v[2], v[3]));
            if ((oc & 1) == 0) pend = (uint32_t)(uint16_t)(short)m;
            else m16[(size_t)(oc >> 1) * TOTAL + p] = pend | ((uint32_t)(uint16_t)(short)m << 16);
        }
    }
}

// ---------------- integer BN stats over m16 planes ----------------
template<int PIXELS, int CHUNKS>
__global__ __launch_bounds__(256) void stats16_kernel(const uint32_t* __restrict__ m16,
                                                      double* __restrict__ pd)
{
    __shared__ int wb[4][4];
    int bid = blockIdx.x;
    int q = bid / CHUNKS, ch = bid % CHUNKS;
    const uint32_t* pl = m16 + (size_t)q * PIXELS + (size_t)ch * (PIXELS / CHUNKS);
    int tid = threadIdx.x;
    int s0 = 0, s1 = 0, q0 = 0, q1 = 0;
    #pragma unroll 4
    for (int j = 0; j < PIXELS / CHUNKS / 256; ++j) {
        uint32_t u = pl[tid + j * 256];
        int m0 = (int)(short)(u & 0xffffu);
        int m1 = (int)u >> 16;
        s0 += m0; s1 += m1;
        q0 += m0 * m0; q1 += m1 * m1;
    }
    #pragma unroll
    for (int off = 32; off >= 1; off >>= 1) {
        s0 += __shfl_xor(s0, off, 64); s1 += __shfl_xor(s1, off, 64);
        q0 += __shfl_xor(q0, off, 64); q1 += __shfl_xor(q1, off, 64);
    }
    int lane = tid & 63, w = tid >> 6;
    if (lane == 0) { wb[w][0] = s0; wb[w][1] = s1; wb[w][2] = q0; wb[w][3] = q1; }
    __syncthreads();
    if (tid < 4)
        pd[(size_t)bid * 4 + tid] =
            (double)((long long)wb[0][tid] + wb[1][tid] + wb[2][tid] + wb[3][tid]);
}

// merged: reduce chunk partials + compute BN scale/shift (exact integer doubles)
template<int OC, int CHUNKS>
__global__ void finalize16_kernel(const double* __restrict__ pd,
                                  const float* __restrict__ gamma, const float* __restrict__ beta,
                                  const float* __restrict__ alpha,
                                  float inv_n, float* __restrict__ ss)
{
    __shared__ double sums[2 * OC];
    int tid = threadIdx.x;
    if (tid < 2 * OC) {
        bool issq = tid >= OC;
        int c = issq ? tid - OC : tid;
        int q = c >> 1;
        int slot = (issq ? 2 : 0) + (c & 1);
        double a = 0.0;
        #pragma unroll 4
        for (int i = 0; i < CHUNKS; ++i)
            a += pd[(size_t)(q * CHUNKS + i) * 4 + slot];
        sums[tid] = a;
    }
    __syncthreads();
    if (tid < OC) {
        double al = (double)alpha[0];
        float mu  = (float)(sums[tid] * al * (double)inv_n);
        float ex2 = (float)(sums[OC + tid] * al * al * (double)inv_n);
        float var = ex2 - mu * mu;
        float A = gamma[tid] * (1.f / sqrtf(var + 1e-5f));
        ss[tid] = A;
        ss[OC + tid] = beta[tid] - mu * A;
    }
}

// ---------------- thin pack: int16 -> BN threshold -> sign bits ----------------
template<int OC, int PW, int LPW, bool PADOUT>
__global__ __launch_bounds__(256) void binconv_pack_kernel(
    const uint32_t* __restrict__ m16, const float* __restrict__ alpha,
    const float* __restrict__ ss, void* __restrict__ sout)
{
    constexpr int TOTAL = NB * PW * PW;
    __shared__ float Ap[OC], Bp[OC];
    int tid = threadIdx.x;
    if (tid < OC) { Ap[tid] = ss[tid] * alpha[0]; Bp[tid] = ss[OC + tid]; }
    __syncthreads();
    int p = blockIdx.x * 256 + tid;
    uint64_t word = 0;
    #pragma unroll
    for (int q = 0; q < OC / 2; ++q) {
        uint32_t u = m16[(size_t)q * TOTAL + p];
        int m0 = (int)(short)(u & 0xffffu);
        int m1 = (int)u >> 16;
        float v0 = fmaf(Ap[2 * q],     (float)m0, Bp[2 * q]);
        float v1 = fmaf(Ap[2 * q + 1], (float)m1, Bp[2 * q + 1]);
        word |= (v0 > 0.f ? 1ull : 0ull) << (2 * q);
        word |= (v1 > 0.f ? 1ull : 0ull) << (2 * q + 1);
    }
    if constexpr (PADOUT) {
        int px = p & (PW - 1), py = (p >> LPW) & (PW - 1), n = p >> (2 * LPW);
        ((uint32_t*)sout)[(size_t)n * (PW + 2) * (PW + 2) + (py + 1) * (PW + 2) + (px + 1)]
            = (uint32_t)word;
    } else {
        ((uint64_t*)sout)[p] = word;
    }
}

// ---------------- stage 4: binary conv 64->128, slab partials ----------------
__global__ __launch_bounds__(256) void conv4_partial_kernel(
    const uint64_t* __restrict__ s3, const uint64_t* __restrict__ wp4,
    float* __restrict__ p4)
{
    __shared__ uint64_t xt[192];
    __shared__ uint64_t wl[1152];
    __shared__ float red[256];
    int b = blockIdx.x;
    int n = b >> 3, s = b & 7;
    int tid = threadIdx.x;
    for (int i = tid; i < 192; i += 256) {
        int row = 4 * s - 1 + (i >> 5);
        int col = i & 31;
        xt[i] = (row >= 0 && row < 32) ? s3[(size_t)n * 1024 + row * 32 + col] : 0ull;
    }
    for (int i = tid; i < 1152; i += 256) wl[i] = wp4[i];
    __syncthreads();
    int oc = tid & 127, h = tid >> 7;
    uint64_t wr[9];
    #pragma unroll
    for (int t = 0; t < 9; ++t) wr[t] = wl[oc * 9 + t];
    int acc = 0;
    #pragma unroll
    for (int ry = 0; ry < 2; ++ry) {
        int lry = 2 * h + ry;
        int y = 4 * s + lry;
        for (int x = 0; x < 32; ++x) {
            int pop = 0, c = 0;
            #pragma unroll
            for (int ky = 0; ky < 3; ++ky) {
                int yy = y + ky - 1;
                if (yy < 0 || yy >= 32) continue;
                int lrow = lry + ky;
                #pragma unroll
                for (int kx = 0; kx < 3; ++kx) {
                    int xx = x + kx - 1;
                    if (xx < 0 || xx >= 32) continue;
                    pop += __popcll(xt[lrow * 32 + xx] ^ wr[ky * 3 + kx]);
                    c += 64;
                }
            }
            acc += c - 2 * pop;
        }
    }
    red[tid] = (float)acc;
    __syncthreads();
    if (tid < 128)
        p4[(size_t)b * 128 + tid] = red[tid] + red[tid + 128];
}

// ---------------- mean over slabs + classifier, one block per image ----------------
__global__ __launch_bounds__(128) void mean_linear_kernel(
    const float* __restrict__ p4, const float* __restrict__ alpha4,
    const float* __restrict__ wf, const float* __restrict__ bf, float* __restrict__ out)
{
    __shared__ float ml[128];
    int n = blockIdx.x, tid = threadIdx.x;
    float a = 0.f;
    #pragma unroll
    for (int s = 0; s < 8; ++s)
        a += p4[(size_t)((n * 8 + s) * 128) + tid];
    ml[tid] = a * alpha4[0] * (1.f / 1024.f);
    __syncthreads();
    if (tid < 10) {
        const float* w = wf + tid * 128;
        float acc = bf[tid];
        #pragma unroll 4
        for (int i = 0; i < 128; ++i) acc = fmaf(ml[i], w[i], acc);
        out[n * 10 + tid] = acc;
    }
}

extern "C" void kernel_launch(void* const* d_in, const int* in_sizes, int n_in,
                              void* d_out, int out_size, void* d_ws, size_t ws_size,
                              hipStream_t stream)
{
    const float* x   = (const float*)d_in[0];
    const float* w1  = (const float*)d_in[1];
    const float* b1  = (const float*)d_in[2];
    const float* g1  = (const float*)d_in[3];
    const float* be1 = (const float*)d_in[4];
    const float* w2  = (const float*)d_in[5];
    const float* a2  = (const float*)d_in[6];
    const float* g2  = (const float*)d_in[7];
    const float* be2 = (const float*)d_in[8];
    const float* w3  = (const float*)d_in[9];
    const float* a3  = (const float*)d_in[10];
    const float* g3  = (const float*)d_in[11];
    const float* be3 = (const float*)d_in[12];
    const float* w4  = (const float*)d_in[13];
    const float* a4  = (const float*)d_in[14];
    const float* wf  = (const float*)d_in[15];
    const float* bf  = (const float*)d_in[16];
    float* out = (float*)d_out;

    uint8_t* ws = (uint8_t*)d_ws;
    size_t off = 0;
    auto alloc = [&](size_t bytes) -> void* {
        void* p = ws + off;
        off += (bytes + 255) & ~(size_t)255;
        return p;
    };
    uint32_t* wp2 = (uint32_t*)alloc(288 * 4);
    uint32_t* wp3 = (uint32_t*)alloc(576 * 4);
    uint32_t* wp4 = (uint32_t*)alloc(2304 * 4);
    float* ss1 = (float*)alloc(64 * 4);
    float* ss2 = (float*)alloc(64 * 4);
    float* ss3 = (float*)alloc(128 * 4);
    double* dsums = (double*)alloc(256 * 8);
    double* pd    = (double*)alloc(2048 * 8);
    float* partials = (float*)alloc((size_t)512 * 64 * 4);
    uint32_t* s1p = (uint32_t*)alloc((size_t)128 * 16900 * 4);   // padded 130x130
    uint32_t* s2p = (uint32_t*)alloc((size_t)128 * 4356 * 4);    // padded 66x66
    uint64_t* s3  = (uint64_t*)alloc((size_t)128 * 1024 * 8);    // unpadded 32x32
    float* p4    = (float*)alloc((size_t)1024 * 128 * 4);
    uint32_t* m16_2 = (uint32_t*)alloc((size_t)16 * 524288 * 4); // 33.6 MB
    uint32_t* m16_3 = (uint32_t*)alloc((size_t)32 * 131072 * 4); // 16.8 MB

    // zero both padded buffers in one contiguous span (s1p..end of s2p)
    {
        size_t span_bytes = (size_t)((uint8_t*)(s2p + (size_t)128 * 4356) - (uint8_t*)s1p);
        int n4 = (int)(span_bytes / 16);
        zero4_kernel<<<1024, 256, 0, stream>>>((uint4*)s1p, n4);
    }

    // pack all weight signs (one kernel)
    pack_weights_all_kernel<<<13, 256, 0, stream>>>(w2, w3, w4, wp2, wp3, wp4);

    // stage 1: xcorr stats -> BN scale/shift -> conv+sign+pack (padded out)
    xcorr_kernel<<<512, 256, 0, stream>>>(x, partials);
    reduce_partials_kernel<54, 64><<<54, 256, 0, stream>>>(partials, 512, dsums);
    compute_ss1_kernel<<<1, 64, 0, stream>>>(dsums, w1, b1, g1, be1, ss1);
    conv1_pack2_kernel<<<8192, 256, 0, stream>>>(x, w1, b1, ss1, s1p);

    // stage 2: fused main+fix -> int stats -> finalize -> pack (padded out)
    binconv_mainfix_kernel<32, 64, 6, 2048><<<2048 + 126, 256, 0, stream>>>(s1p, wp2, a2, m16_2);
    stats16_kernel<524288, 32><<<512, 256, 0, stream>>>(m16_2, pd);
    finalize16_kernel<32, 32><<<1, 256, 0, stream>>>(pd, g2, be2, a2, 1.f / 524288.f, ss2);
    binconv_pack_kernel<32, 64, 6, true><<<2048, 256, 0, stream>>>(m16_2, a2, ss2, (void*)s2p);

    // stage 3
    binconv_mainfix_kernel<64, 32, 5, 512><<<512 + 62, 256, 0, stream>>>(s2p, wp3, a3, m16_3);
    stats16_kernel<131072, 8><<<256, 256, 0, stream>>>(m16_3, pd);
    finalize16_kernel<64, 8><<<1, 256, 0, stream>>>(pd, g3, be3, a3, 1.f / 131072.f, ss3);
    binconv_pack_kernel<64, 32, 5, false><<<512, 256, 0, stream>>>(m16_3, a3, ss3, (void*)s3);

    // stage 4: slab partials -> mean+classifier
    conv4_partial_kernel<<<1024, 256, 0, stream>>>(s3, (const uint64_t*)wp4, p4);
    mean_linear_kernel<<<128, 128, 0, stream>>>(p4, a4, wf, bf, out);
}